// Round 4
// baseline (139.857 us; speedup 1.0000x reference)
//
#include <hip/hip_runtime.h>
#include <hip/hip_bf16.h>
#include <cstdint>

#define N_PTS 8192
#define DIM 128
#define NBLOCKS 2080  // 64*65/2 upper-triangle tile blocks

typedef __attribute__((ext_vector_type(8))) __bf16 bf16x8;
typedef __attribute__((ext_vector_type(4))) float f32x4;

// base-2 logit constants: l2 = l/ln2
#define K_A 369.32995f  // 256/ln2
#define K_B 738.65990f  // 512/ln2
#define K_C 346.24683f  // 240/ln2
#define K_D 23.083122f  // 16/ln2
#define LN2 0.69314718f

// lp2(s) = (256 s^2 - 512 s + 240)/ln2, monotone decreasing for s < 1
__device__ __forceinline__ float lp2_of(float s) {
  return __builtin_fmaf(s, __builtin_fmaf(s, K_A, -K_B), K_C);
}
// base-2 lse merge: s <- s*2^(m-mm) + s2*2^(m2-mm)
__device__ __forceinline__ void lse_merge2(float& m, float& s, float m2, float s2) {
  const float mm = fmaxf(m, m2);
  s = __builtin_fmaf(s, __builtin_amdgcn_exp2f(m - mm),
                     s2 * __builtin_amdgcn_exp2f(m2 - mm));
  m = mm;
}

// RNE float -> bf16 bits (inputs finite)
__device__ __forceinline__ unsigned short f2bf(float x) {
  unsigned int u = __float_as_uint(x);
  return (unsigned short)((u + 0x7FFFu + ((u >> 16) & 1u)) >> 16);
}

// One wave per row: L2-normalize (eps=1e-12), store bf16 bits; zero counter.
__global__ __launch_bounds__(256) void normalize_kernel(const float* __restrict__ feat,
                                                        unsigned short* __restrict__ fb,
                                                        int* __restrict__ counter) {
  if (blockIdx.x == 0 && threadIdx.x == 0) *counter = 0;
  const int row = blockIdx.x * 4 + (threadIdx.x >> 6);
  const int lane = threadIdx.x & 63;
  const float2 v = *(const float2*)(feat + row * DIM + lane * 2);
  float ss = v.x * v.x + v.y * v.y;
#pragma unroll
  for (int o = 32; o > 0; o >>= 1) ss += __shfl_xor(ss, o);
  const float inv = 1.0f / fmaxf(sqrtf(ss), 1e-12f);
  const unsigned int pack =
      (unsigned int)f2bf(v.x * inv) | ((unsigned int)f2bf(v.y * inv) << 16);
  *(unsigned int*)(fb + row * DIM + lane * 2) = pack;
}

// Two-pass epilogue: pass1 = raw-sim extremes + eqmask pack (no logits, no exp);
// pass2 = one exp2 per element. acc (32 VGPRs) stays live across the reduce.
template <bool DIAG>
__device__ __forceinline__ void epilogue(const f32x4 (&acc)[4][2],
                                         const int* __restrict__ labels, int ibase,
                                         int dj, const int (&lj)[2], int lane, int wave,
                                         int t, int k, float* redA, float* redB,
                                         float4* __restrict__ partials,
                                         int* __restrict__ counter, int* lastflag) {
  // ---- pass 1 ----
  float minP = 1e30f, cN = 0.f;
  unsigned int eqm = 0;
#pragma unroll
  for (int tm = 0; tm < 4; ++tm) {
    const int4 liv = *(const int4*)(labels + ibase + tm * 16);
    const int li[4] = {liv.x, liv.y, liv.z, liv.w};
#pragma unroll
    for (int tn = 0; tn < 2; ++tn) {
#pragma unroll
      for (int r = 0; r < 4; ++r) {
        const float s = acc[tm][tn][r];
        const bool eq = (li[r] == lj[tn]);
        eqm |= (eq ? 1u : 0u) << (((tm * 2 + tn) << 2) + r);
        bool pm = eq, nm = !eq;
        if (DIAG) {
          const bool valid = (dj + tn * 16 - tm * 16 - r) > 0;
          pm = pm && valid;
          nm = nm && valid;
        }
        minP = fminf(minP, pm ? s : 1e30f);
        const float u = fmaxf(s, -0.25f);
        cN = fmaxf(cN, nm ? fabsf(u) : 0.f);
      }
    }
  }
#pragma unroll
  for (int o = 32; o > 0; o >>= 1) {
    minP = fminf(minP, __shfl_xor(minP, o));
    cN = fmaxf(cN, __shfl_xor(cN, o));
  }
  if (lane == 0) { redA[wave] = minP; redB[wave] = cN; }
  __syncthreads();
  float bm = 1e30f, bc = 0.f;
#pragma unroll
  for (int w = 0; w < 8; ++w) {
    bm = fminf(bm, redA[w]);
    bc = fmaxf(bc, redB[w]);
  }
  // block-wide stream maxima (base-2). empty pos -> lp2_of(1e30)=+inf (safe: only
  // produces exp2(-inf)=0 terms); empty neg -> -23.08 bound with Sn=0 (clamped).
  const float Mp2 = lp2_of(bm);
  const float Mn2 = __builtin_fmaf(bc * bc, K_A, -K_D);
  __syncthreads();  // redA/redB reuse

  // ---- pass 2 ----
  float spA[4] = {0.f, 0.f, 0.f, 0.f}, snA[4] = {0.f, 0.f, 0.f, 0.f};
#pragma unroll
  for (int tm = 0; tm < 4; ++tm) {
#pragma unroll
    for (int tn = 0; tn < 2; ++tn) {
      const int vbase = DIAG ? (dj + tn * 16 - tm * 16) : 0;
#pragma unroll
      for (int r = 0; r < 4; ++r) {
        const float s = acc[tm][tn][r];
        const bool eq = (eqm & (1u << (((tm * 2 + tn) << 2) + r))) != 0u;
        const float lP = lp2_of(s);
        const float u = fmaxf(s, -0.25f);
        const float lN = __builtin_fmaf(u * u, K_A, -K_D);
        const float l = eq ? lP : lN;
        const float m = eq ? Mp2 : Mn2;
        float e = __builtin_amdgcn_exp2f(l - m);
        if (DIAG) e = (vbase > r) ? e : 0.f;
        const float ep = eq ? e : 0.f;
        spA[r] += ep;
        snA[r] += e - ep;
      }
    }
  }
  float sp = (spA[0] + spA[1]) + (spA[2] + spA[3]);
  float sn = (snA[0] + snA[1]) + (snA[2] + snA[3]);
#pragma unroll
  for (int o = 32; o > 0; o >>= 1) {
    sp += __shfl_xor(sp, o);
    sn += __shfl_xor(sn, o);
  }
  if (lane == 0) { redA[wave] = sp; redB[wave] = sn; }
  __syncthreads();
  if (t == 0) {
    float Sp = 0.f, Sn = 0.f;
#pragma unroll
    for (int w = 0; w < 8; ++w) { Sp += redA[w]; Sn += redB[w]; }
    // clamp empty streams so their m never dominates the cross-block merge
    partials[k] = make_float4(Sp == 0.f ? -1e30f : Mp2, Sp,
                              Sn == 0.f ? -1e30f : Mn2, Sn);
    __threadfence();
    *lastflag = (atomicAdd(counter, 1) == NBLOCKS - 1);
  }
}

// 128x128 tile per block, 512 threads (8 waves of 64x32), upper-triangle tiles.
__global__ __launch_bounds__(512, 4) void pair_kernel(const unsigned short* __restrict__ f,
                                                      const int* __restrict__ labels,
                                                      float4* __restrict__ partials,
                                                      int* __restrict__ counter,
                                                      float* __restrict__ out) {
  // decode linear block id -> (tI, tJ), tJ >= tI
  const int k = blockIdx.x;
  int tI = (int)((129.0 - sqrt(16641.0 - 8.0 * (double)k)) * 0.5);
  tI = tI < 0 ? 0 : (tI > 63 ? 63 : tI);
  while (64 * (tI + 1) - ((tI + 1) * tI) / 2 <= k) ++tI;
  while (64 * tI - (tI * (tI - 1)) / 2 > k) --tI;
  const int tJ = tI + (k - (64 * tI - (tI * (tI - 1)) / 2));

  __shared__ uint4 sAq[512];  // 8 KB
  __shared__ uint4 sBq[512];  // 8 KB
  __shared__ float redA[8], redB[8];
  __shared__ float4 fred[8];
  __shared__ int lastflag;

  const int t = threadIdx.x;
  const int lane = t & 63, wave = t >> 6;
  const int wri = wave >> 2, wci = wave & 3;  // wave tile: rows wri*64, cols wci*32
  const int rowA0 = tI * 128, rowB0 = tJ * 128;

  // staging: thread t owns 16B chunk t of each 128x32 slab (chunk-linear layout)
  const int rstage = ((t >> 6) << 4) + (t & 15);
  const int kcs = ((t >> 4) & 3) * 8;
  const unsigned short* gA = f + (size_t)(rowA0 + rstage) * DIM + kcs;
  const unsigned short* gB = f + (size_t)(rowB0 + rstage) * DIM + kcs;

  f32x4 acc[4][2];
#pragma unroll
  for (int a = 0; a < 4; ++a)
#pragma unroll
    for (int b = 0; b < 2; ++b) acc[a][b] = (f32x4){0.f, 0.f, 0.f, 0.f};

#pragma unroll
  for (int kk = 0; kk < 4; ++kk) {
    if (kk) __syncthreads();
    __builtin_amdgcn_global_load_lds(
        (const __attribute__((address_space(1))) unsigned int*)(gA + kk * 32),
        (__attribute__((address_space(3))) unsigned int*)(sAq + t), 16, 0, 0);
    __builtin_amdgcn_global_load_lds(
        (const __attribute__((address_space(1))) unsigned int*)(gB + kk * 32),
        (__attribute__((address_space(3))) unsigned int*)(sBq + t), 16, 0, 0);
    __syncthreads();  // drains vmcnt -> LDS visible
    bf16x8 fa[4], fbv[2];
#pragma unroll
    for (int x = 0; x < 4; ++x)
      fa[x] = ((const bf16x8*)sAq)[((wri * 4 + x) << 6) + lane];
#pragma unroll
    for (int y = 0; y < 2; ++y)
      fbv[y] = ((const bf16x8*)sBq)[((wci * 2 + y) << 6) + lane];
#pragma unroll
    for (int tm = 0; tm < 4; ++tm)
#pragma unroll
      for (int tn = 0; tn < 2; ++tn)
        acc[tm][tn] =
            __builtin_amdgcn_mfma_f32_16x16x32_bf16(fa[tm], fbv[tn], acc[tm][tn], 0, 0, 0);
  }

  // C/D mapping (16x16x32): col = lane&15, row = (lane>>4)*4 + reg
  const int ibase = rowA0 + wri * 64 + (lane >> 4) * 4;
  const int jbase = rowB0 + wci * 32 + (lane & 15);
  const int dj = jbase - ibase;
  int lj[2];
  lj[0] = labels[jbase];
  lj[1] = labels[jbase + 16];

  if (tI == tJ) {
    epilogue<true>(acc, labels, ibase, dj, lj, lane, wave, t, k, redA, redB, partials,
                   counter, &lastflag);
  } else {
    epilogue<false>(acc, labels, ibase, dj, lj, lane, wave, t, k, redA, redB, partials,
                    counter, &lastflag);
  }
  __syncthreads();
  if (!lastflag) return;

  // ---- last block: merge all partials (base-2), softplus, write out ----
  __threadfence();  // acquire: see other blocks' partials
  float Mp = -1e30f, Sp = 0.f, Mn = -1e30f, Sn = 0.f;
  for (int i = t; i < NBLOCKS; i += 512) {
    const float4 p = partials[i];
    lse_merge2(Mp, Sp, p.x, p.y);
    lse_merge2(Mn, Sn, p.z, p.w);
  }
#pragma unroll
  for (int o = 32; o > 0; o >>= 1) {
    const float am = __shfl_xor(Mp, o), as = __shfl_xor(Sp, o);
    lse_merge2(Mp, Sp, am, as);
    const float bm = __shfl_xor(Mn, o), bs = __shfl_xor(Sn, o);
    lse_merge2(Mn, Sn, bm, bs);
  }
  if (lane == 0) fred[wave] = make_float4(Mp, Sp, Mn, Sn);
  __syncthreads();
  if (t == 0) {
    float mpf = -1e30f, spf = 0.f, mnf = -1e30f, snf = 0.f;
#pragma unroll
    for (int w = 0; w < 8; ++w) {
      const float4 q = fred[w];
      lse_merge2(mpf, spf, q.x, q.y);
      lse_merge2(mnf, snf, q.z, q.w);
    }
    // convert base-2 lse to natural: m*ln2 + ln(S)
    const float x = (mpf + mnf) * LN2 + logf(spf) + logf(snf);
    out[0] = fmaxf(x, 0.f) + log1pf(__expf(-fabsf(x)));  // stable softplus
  }
}

extern "C" void kernel_launch(void* const* d_in, const int* in_sizes, int n_in,
                              void* d_out, int out_size, void* d_ws, size_t ws_size,
                              hipStream_t stream) {
  const float* feat = (const float*)d_in[0];
  const int* labels = (const int*)d_in[1];
  float* out = (float*)d_out;

  unsigned short* fb = (unsigned short*)d_ws;  // 2 MB
  float4* partials = (float4*)((char*)d_ws + (size_t)N_PTS * DIM * 2);
  int* counter = (int*)((char*)d_ws + (size_t)N_PTS * DIM * 2 + NBLOCKS * sizeof(float4));

  normalize_kernel<<<N_PTS / 4, 256, 0, stream>>>(feat, fb, counter);
  pair_kernel<<<NBLOCKS, 512, 0, stream>>>(fb, labels, partials, counter, out);
}